// Round 3
// baseline (247.015 us; speedup 1.0000x reference)
//
#include <hip/hip_runtime.h>
#include <stdint.h>

// Problem constants (fixed by setup_inputs)
#define BATCH 32
#define CH    256
#define MID   64
#define HW    3136   // 56*56
#define HWV   784    // HW / 4 (float4 vectors per plane)

typedef __attribute__((ext_vector_type(4))) float fvec4;

// Kernel 1: global average pool. One block per (b,c) plane of 3136 elems.
// Regular (caching) loads on purpose: x should stay L3-resident for kernel 2.
__global__ __launch_bounds__(256) void se_pool(const fvec4* __restrict__ x,
                                               float* __restrict__ pooled) {
    const int p = blockIdx.x;                 // plane index = b*CH + c
    const fvec4* base = x + (size_t)p * HWV;
    const int t = threadIdx.x;

    float sum = 0.0f;
    for (int i = t; i < HWV; i += 256) {
        fvec4 v = base[i];
        sum += v.x + v.y + v.z + v.w;
    }
    #pragma unroll
    for (int off = 32; off > 0; off >>= 1) sum += __shfl_down(sum, off, 64);

    __shared__ float part[4];
    if ((t & 63) == 0) part[t >> 6] = sum;
    __syncthreads();
    if (t == 0) {
        pooled[p] = (part[0] + part[1] + part[2] + part[3]) * (1.0f / (float)HW);
    }
}

// Kernel 2: fused gate + scale. One block per (b,c) plane.
// Each block redundantly computes h[0..63] for its batch (cheap: 16K MACs,
// w1 is L1/L2-hot), derives its single gate value, then streams the plane.
// out stores are non-temporal so they don't evict x from L2/L3.
__global__ __launch_bounds__(256) void se_gate_scale(
    const fvec4* __restrict__ x,
    const float* __restrict__ pooled,
    const float* __restrict__ w1, const float* __restrict__ b1,
    const float* __restrict__ w2, const float* __restrict__ b2,
    fvec4* __restrict__ out) {
    const int p = blockIdx.x;
    const int b = p >> 8;      // / CH
    const int c = p & 255;     // % CH
    const int t = threadIdx.x;
    const int m = t & 63;      // which hidden unit
    const int q = t >> 6;      // which quarter of the 256 channels

    __shared__ float ps[CH];
    __shared__ float hp[4][MID];
    __shared__ float hs[MID];
    __shared__ float gsh;

    ps[t] = pooled[b * CH + t];
    __syncthreads();

    // h partials: thread (q,m) dots 64 channels of w1 row m against ps.
    {
        float acc = 0.0f;
        const fvec4* wrow = (const fvec4*)(w1 + m * CH + q * 64);
        const float* pq = ps + q * 64;
        #pragma unroll
        for (int i = 0; i < 16; ++i) {
            fvec4 wv = wrow[i];
            acc += pq[4 * i + 0] * wv.x + pq[4 * i + 1] * wv.y +
                   pq[4 * i + 2] * wv.z + pq[4 * i + 3] * wv.w;
        }
        hp[q][m] = acc;
    }
    __syncthreads();
    if (t < MID) {
        hs[t] = fmaxf(b1[t] + hp[0][t] + hp[1][t] + hp[2][t] + hp[3][t], 0.0f);
    }
    __syncthreads();
    // y_c = dot(h, w2 row c) via one wave's shuffle reduction.
    if (t < 64) {
        float v = hs[t] * w2[c * MID + t];
        #pragma unroll
        for (int off = 32; off > 0; off >>= 1) v += __shfl_down(v, off, 64);
        if (t == 0) {
            gsh = fminf(fmaxf(v + b2[c] + 3.0f, 0.0f), 6.0f) * 0.16666667f;
        }
    }
    __syncthreads();
    const float g = gsh;

    const fvec4* xb = x + (size_t)p * HWV;
    fvec4* ob = out + (size_t)p * HWV;
    for (int i = t; i < HWV; i += 256) {
        fvec4 v = xb[i];
        fvec4 r = { v.x * g, v.y * g, v.z * g, v.w * g };
        __builtin_nontemporal_store(r, ob + i);
    }
}

extern "C" void kernel_launch(void* const* d_in, const int* in_sizes, int n_in,
                              void* d_out, int out_size, void* d_ws, size_t ws_size,
                              hipStream_t stream) {
    (void)in_sizes; (void)n_in; (void)out_size; (void)ws_size;

    const float* x  = (const float*)d_in[0];
    const float* w1 = (const float*)d_in[1];
    const float* b1 = (const float*)d_in[2];
    const float* w2 = (const float*)d_in[3];
    const float* b2 = (const float*)d_in[4];

    float* pooled = (float*)d_ws;   // BATCH*CH floats = 32 KB

    se_pool<<<BATCH * CH, 256, 0, stream>>>((const fvec4*)x, pooled);
    se_gate_scale<<<BATCH * CH, 256, 0, stream>>>((const fvec4*)x, pooled,
                                                  w1, b1, w2, b2, (fvec4*)d_out);
}

// Round 5
// 211.418 us; speedup vs baseline: 1.1684x; 1.1684x over previous
//
#include <hip/hip_runtime.h>
#include <stdint.h>

// Problem constants (fixed by setup_inputs)
#define BATCH 32
#define CH    256
#define MID   64
#define HW    3136   // 56*56
#define HWV   784    // float4 vectors per plane (3136/4 = 3*256 + 16)

typedef __attribute__((ext_vector_type(4))) float fvec4;

// Kernel 1: global average pool fused with the SQUEEZE GEMV column.
// One block per (b,c) plane. Block (b,c) owns column c of w1:
//   hpre[b,m] += pooled[b,c] * w1[m,c]   (64 atomicAdds, addresses L2-hot)
// This removes the separate gate kernel without replicating the w1 read
// pattern across 8192 blocks (round-3 regression root cause).
__global__ __launch_bounds__(256) void se_pool_h(const fvec4* __restrict__ x,
                                                 const float* __restrict__ w1,
                                                 float* __restrict__ hpre) {
    const int p = blockIdx.x;          // plane = b*CH + c
    const int b = p >> 8;
    const int c = p & 255;
    const int t = threadIdx.x;

    const fvec4* base = x + (size_t)p * HWV;
    float sum = 0.0f;
    for (int i = t; i < HWV; i += 256) {
        fvec4 v = base[i];
        sum += v.x + v.y + v.z + v.w;
    }
    #pragma unroll
    for (int off = 32; off > 0; off >>= 1) sum += __shfl_down(sum, off, 64);

    __shared__ float part[4];
    if ((t & 63) == 0) part[t >> 6] = sum;
    __syncthreads();

    if (t < MID) {
        const float pv =
            (part[0] + part[1] + part[2] + part[3]) * (1.0f / (float)HW);
        // lane m accumulates this channel's contribution to hidden unit m
        atomicAdd(&hpre[b * MID + t], pv * w1[t * CH + c]);
    }
}

// Kernel 2: finish the expand GEMV for this plane's channel, then scale.
// w2 row c is 64 CONTIGUOUS floats (single line-pair, L2-hot) — cheap.
// Plane loads are issued before the gate math so gate latency hides under
// the global-load latency. NT stores keep `out` from evicting x in L3.
__global__ __launch_bounds__(256) void se_scale(const fvec4* __restrict__ x,
                                                const float* __restrict__ hpre,
                                                const float* __restrict__ b1,
                                                const float* __restrict__ w2,
                                                const float* __restrict__ b2,
                                                fvec4* __restrict__ out) {
    const int p = blockIdx.x;
    const int b = p >> 8;
    const int c = p & 255;
    const int t = threadIdx.x;

    // issue plane loads first (784 = 3*256 + 16)
    const fvec4* xb = x + (size_t)p * HWV;
    fvec4 v0 = xb[t];
    fvec4 v1 = xb[t + 256];
    fvec4 v2 = xb[t + 512];
    fvec4 v3 = {0.f, 0.f, 0.f, 0.f};
    if (t < 16) v3 = xb[t + 768];

    // gate: g = hsig(b2[c] + sum_m relu(hpre[b,m]+b1[m]) * w2[c,m])
    __shared__ float gsh;
    if (t < MID) {
        float hv = fmaxf(hpre[b * MID + t] + b1[t], 0.0f);
        float yv = hv * w2[c * MID + t];
        #pragma unroll
        for (int off = 32; off > 0; off >>= 1) yv += __shfl_down(yv, off, 64);
        if (t == 0) {
            gsh = fminf(fmaxf(yv + b2[c] + 3.0f, 0.0f), 6.0f) * 0.16666667f;
        }
    }
    __syncthreads();
    const float g = gsh;

    fvec4* ob = out + (size_t)p * HWV;
    __builtin_nontemporal_store(v0 * g, ob + t);
    __builtin_nontemporal_store(v1 * g, ob + t + 256);
    __builtin_nontemporal_store(v2 * g, ob + t + 512);
    if (t < 16) __builtin_nontemporal_store(v3 * g, ob + t + 768);
}

extern "C" void kernel_launch(void* const* d_in, const int* in_sizes, int n_in,
                              void* d_out, int out_size, void* d_ws, size_t ws_size,
                              hipStream_t stream) {
    (void)in_sizes; (void)n_in; (void)out_size; (void)ws_size;

    const float* x  = (const float*)d_in[0];
    const float* w1 = (const float*)d_in[1];
    const float* b1 = (const float*)d_in[2];
    const float* w2 = (const float*)d_in[3];
    const float* b2 = (const float*)d_in[4];

    float* hpre = (float*)d_ws;   // BATCH*MID floats = 8 KB, must be zeroed

    hipMemsetAsync(hpre, 0, BATCH * MID * sizeof(float), stream);
    se_pool_h<<<BATCH * CH, 256, 0, stream>>>((const fvec4*)x, w1, hpre);
    se_scale<<<BATCH * CH, 256, 0, stream>>>((const fvec4*)x, hpre,
                                             b1, w2, b2, (fvec4*)d_out);
}